// Round 1
// baseline (1069.609 us; speedup 1.0000x reference)
//
#include <hip/hip_runtime.h>
#include <math.h>

// Retinex MSR: img (16,3,512,512) fp32 -> per-channel min-max stretched
// sum_sigma log(gauss_blur(img, sigma)+1)/3, sigmas {15,80,250},
// separable zero-padded convs, K = {91,481,1501}, R = {45,240,750}.

#define HH 512
#define WW 512
#define NSL 48  // B*C slices

// d_ws layout in floats:
#define W0_OFF 0      // sigma 15 padded weights, alloc 512  (16 zero | 91 w | zeros)
#define W1_OFF 512    // sigma 80 padded weights, alloc 768  (16 zero | 481 w | zeros)
#define W2_OFF 1280   // sigma 250 padded weights, alloc 1536 (16 zero | 1501 w | zeros)
#define MM_OFF 2816   // 6 uints: min[3], max[3]
#define TMP_OFF 4096  // tmp blur buffer, 48*512*512 floats

// ---------------- weights ----------------
__global__ void wkern(float* __restrict__ ws) {
  __shared__ float red[256];
  const int s = blockIdx.x;
  const int Ks[3] = {91, 481, 1501};
  const float sg[3] = {15.f, 80.f, 250.f};
  const int off[3] = {W0_OFF, W1_OFF, W2_OFF};
  const int alloc[3] = {512, 768, 1536};
  const int K = Ks[s], A = alloc[s];
  float* wb = ws + off[s];
  const int t = threadIdx.x;
  for (int i = t; i < A; i += 256) wb[i] = 0.f;
  __syncthreads();
  const float inv2s2 = 1.f / (2.f * sg[s] * sg[s]);
  float part = 0.f;
  for (int i = t; i < K; i += 256) {
    const float d = (float)(i - K / 2);
    const float e = expf(-d * d * inv2s2);
    wb[16 + i] = e;
    part += e;
  }
  red[t] = part;
  __syncthreads();
  for (int st = 128; st > 0; st >>= 1) {
    if (t < st) red[t] += red[t + st];
    __syncthreads();
  }
  const float inv = 1.f / red[0];
  for (int i = t; i < K; i += 256) wb[16 + i] *= inv;
}

__global__ void mm_init(unsigned* __restrict__ mm) {
  const int t = threadIdx.x;
  if (t < 3) mm[t] = 0xFFFFFFFFu;       // min slots
  else if (t < 6) mm[t] = 0u;           // max slots (values >= 0)
}

// ---------------- vertical pass ----------------
// 128 threads, tile 16 y x 512 x, 4 px/thread. Weights wave-uniform.
template <int R>
__global__ __launch_bounds__(128) void vconv(const float* __restrict__ img,
                                             float* __restrict__ tmp,
                                             const float* __restrict__ wpad) {
  const int t = threadIdx.x;
  const int x4 = t << 2;
  const int y0 = blockIdx.x << 4;
  const int n = blockIdx.y;
  const float* src = img + ((size_t)n << 18);
  float4 acc[16];
#pragma unroll
  for (int i = 0; i < 16; ++i) acc[i] = make_float4(0.f, 0.f, 0.f, 0.f);
  const int jlo = (y0 - R) > 0 ? (y0 - R) : 0;
  const int jhi = (y0 + 15 + R) < (HH - 1) ? (y0 + 15 + R) : (HH - 1);
  for (int j = jlo; j <= jhi; ++j) {
    const float4 v = *reinterpret_cast<const float4*>(src + (j << 9) + x4);
    const float* wr = wpad + (j - y0 + R + 16);
#pragma unroll
    for (int yy = 0; yy < 16; ++yy) {
      const float wv = wr[-yy];  // uniform (j, y0 uniform)
      acc[yy].x += wv * v.x;
      acc[yy].y += wv * v.y;
      acc[yy].z += wv * v.z;
      acc[yy].w += wv * v.w;
    }
  }
  float* dst = tmp + ((size_t)n << 18) + (y0 << 9) + x4;
#pragma unroll
  for (int yy = 0; yy < 16; ++yy)
    *reinterpret_cast<float4*>(dst + (yy << 9)) = acc[yy];
}

// ---------------- horizontal pass, window-loop variant (sigma 15/80) ----------------
// One row per block, LDS row padded by R (left) / R+4 (right) zeros.
// Thread owns outputs x=4t..4t+3; one ds_read_b128 -> 16 FMA; weights uniform.
template <int R, bool FIRST>
__global__ __launch_bounds__(128) void hconvA(const float* __restrict__ tmp,
                                              float* __restrict__ out,
                                              const float* __restrict__ wpad) {
  constexpr int PSZ = WW + 2 * R + 4;
  constexpr int S = (2 * R + 7) / 4;  // ceil((2R+4)/4)
  __shared__ __align__(16) float P[PSZ];
  const int t = threadIdx.x;
  const int y = blockIdx.x;
  const int n = blockIdx.y;
  const float* row = tmp + ((size_t)n << 18) + (y << 9);
  for (int i = t; i < PSZ; i += 128) {
    const int j = i - R;
    P[i] = (j >= 0 && j < WW) ? row[j] : 0.f;
  }
  __syncthreads();
  float a0 = 0.f, a1 = 0.f, a2 = 0.f, a3 = 0.f;
  const int c0 = t << 2;
  for (int s = 0; s < S; ++s) {
    const float4 p = *reinterpret_cast<const float4*>(&P[c0 + (s << 2)]);
    const float* wbp = wpad + (s << 2) + 16;  // uniform
    a0 += wbp[0] * p.x + wbp[1] * p.y + wbp[2] * p.z + wbp[3] * p.w;
    a1 += wbp[-1] * p.x + wbp[0] * p.y + wbp[1] * p.z + wbp[2] * p.w;
    a2 += wbp[-2] * p.x + wbp[-1] * p.y + wbp[0] * p.z + wbp[1] * p.w;
    a3 += wbp[-3] * p.x + wbp[-2] * p.y + wbp[-1] * p.z + wbp[0] * p.w;
  }
  const float w3 = 1.f / 3.f;
  float4 res;
  res.x = w3 * logf(a0 + 1.f);
  res.y = w3 * logf(a1 + 1.f);
  res.z = w3 * logf(a2 + 1.f);
  res.w = w3 * logf(a3 + 1.f);
  float* op = out + ((size_t)n << 18) + (y << 9) + (t << 2);
  if (!FIRST) {
    const float4 prev = *reinterpret_cast<const float4*>(op);
    res.x += prev.x;
    res.y += prev.y;
    res.z += prev.z;
    res.w += prev.w;
  }
  *reinterpret_cast<float4*>(op) = res;
}

// ---------------- horizontal pass, dense variant (sigma 250, R=750 >= 511) ----------------
// Every output = weighted sum of the WHOLE row. Row values wave-uniform (scalar
// loads), per-lane weights staged in LDS (stride-16B reads, conflict-free).
__global__ __launch_bounds__(128) void hconvB(const float* __restrict__ tmp,
                                              float* __restrict__ out,
                                              const float* __restrict__ w2g) {
  __shared__ __align__(16) float Wl[1536];  // Wl[i] = w_true[i-9], zero outside
  const int t = threadIdx.x;
  const int y = blockIdx.x;
  const int n = blockIdx.y;
  for (int i = t; i < 1536; i += 128) {
    const int gi = i + 7;  // w2g[j]: j<16 zero | [16,1517) = w_true[j-16] | zeros
    Wl[i] = (gi < 1536) ? w2g[gi] : 0.f;
  }
  __syncthreads();
  const float* row = tmp + ((size_t)n << 18) + (y << 9);
  float a0 = 0.f, a1 = 0.f, a2 = 0.f, a3 = 0.f;
  const int base = 756 - (t << 2);  // 16B-aligned LDS index per lane
  for (int c = 0; c < WW; c += 4) {
    const float4 rv = *reinterpret_cast<const float4*>(&row[c]);  // uniform
    const float* wl = &Wl[c + base];
    // a_k += w_true[c+m - (4t+k) + 750] * rv[m] ; Wl idx = c+base+3+(m-k)
    a0 += wl[3] * rv.x + wl[4] * rv.y + wl[5] * rv.z + wl[6] * rv.w;
    a1 += wl[2] * rv.x + wl[3] * rv.y + wl[4] * rv.z + wl[5] * rv.w;
    a2 += wl[1] * rv.x + wl[2] * rv.y + wl[3] * rv.z + wl[4] * rv.w;
    a3 += wl[0] * rv.x + wl[1] * rv.y + wl[2] * rv.z + wl[3] * rv.w;
  }
  const float w3 = 1.f / 3.f;
  float4 res;
  res.x = w3 * logf(a0 + 1.f);
  res.y = w3 * logf(a1 + 1.f);
  res.z = w3 * logf(a2 + 1.f);
  res.w = w3 * logf(a3 + 1.f);
  float* op = out + ((size_t)n << 18) + (y << 9) + (t << 2);
  const float4 prev = *reinterpret_cast<const float4*>(op);
  res.x += prev.x;
  res.y += prev.y;
  res.z += prev.z;
  res.w += prev.w;
  *reinterpret_cast<float4*>(op) = res;
}

// ---------------- per-channel min/max + normalize ----------------
__global__ __launch_bounds__(256) void minmax_k(const float* __restrict__ r,
                                                unsigned* __restrict__ mm) {
  __shared__ float smn[256], smx[256];
  const int b = blockIdx.x;          // 768 = 48 slices * 16 pieces
  const int slice = b >> 4;
  const int piece = b & 15;
  const int ch = slice % 3;
  const float* p = r + ((size_t)slice << 18) + (piece << 14);
  const int t = threadIdx.x;
  float mn = 3.4e38f, mx = -3.4e38f;
  for (int q = 0; q < 16; ++q) {
    const float4 v = *reinterpret_cast<const float4*>(&p[(q * 256 + t) << 2]);
    mn = fminf(mn, fminf(fminf(v.x, v.y), fminf(v.z, v.w)));
    mx = fmaxf(mx, fmaxf(fmaxf(v.x, v.y), fmaxf(v.z, v.w)));
  }
  smn[t] = mn;
  smx[t] = mx;
  __syncthreads();
  for (int st = 128; st > 0; st >>= 1) {
    if (t < st) {
      smn[t] = fminf(smn[t], smn[t + st]);
      smx[t] = fmaxf(smx[t], smx[t + st]);
    }
    __syncthreads();
  }
  if (t == 0) {
    atomicMin(&mm[ch], __float_as_uint(smn[0]));      // values >= 0: bit order = float order
    atomicMax(&mm[3 + ch], __float_as_uint(smx[0]));
  }
}

__global__ __launch_bounds__(256) void norm_k(float* __restrict__ r,
                                              const unsigned* __restrict__ mm) {
  const int b = blockIdx.x;
  const int slice = b >> 4;
  const int piece = b & 15;
  const int ch = slice % 3;
  const float mn = __uint_as_float(mm[ch]);
  const float mx = __uint_as_float(mm[3 + ch]);
  const float inv = 1.f / (mx - mn);
  float* p = r + ((size_t)slice << 18) + (piece << 14);
  const int t = threadIdx.x;
  for (int q = 0; q < 16; ++q) {
    float4 v = *reinterpret_cast<const float4*>(&p[(q * 256 + t) << 2]);
    v.x = (v.x - mn) * inv;
    v.y = (v.y - mn) * inv;
    v.z = (v.z - mn) * inv;
    v.w = (v.w - mn) * inv;
    *reinterpret_cast<float4*>(&p[(q * 256 + t) << 2]) = v;
  }
}

extern "C" void kernel_launch(void* const* d_in, const int* in_sizes, int n_in,
                              void* d_out, int out_size, void* d_ws, size_t ws_size,
                              hipStream_t stream) {
  const float* img = (const float*)d_in[0];
  float* out = (float*)d_out;
  float* wsf = (float*)d_ws;
  float* tmp = wsf + TMP_OFF;
  unsigned* mm = (unsigned*)(wsf + MM_OFF);

  wkern<<<3, 256, 0, stream>>>(wsf);
  mm_init<<<1, 64, 0, stream>>>(mm);

  dim3 vg(32, NSL);   // y-tiles x slices
  dim3 hg(512, NSL);  // rows x slices

  vconv<45><<<vg, 128, 0, stream>>>(img, tmp, wsf + W0_OFF);
  hconvA<45, true><<<hg, 128, 0, stream>>>(tmp, out, wsf + W0_OFF);

  vconv<240><<<vg, 128, 0, stream>>>(img, tmp, wsf + W1_OFF);
  hconvA<240, false><<<hg, 128, 0, stream>>>(tmp, out, wsf + W1_OFF);

  vconv<750><<<vg, 128, 0, stream>>>(img, tmp, wsf + W2_OFF);
  hconvB<<<hg, 128, 0, stream>>>(tmp, out, wsf + W2_OFF);

  minmax_k<<<768, 256, 0, stream>>>(out, mm);
  norm_k<<<768, 256, 0, stream>>>(out, mm);
}

// Round 3
// 223.466 us; speedup vs baseline: 4.7865x; 4.7865x over previous
//
#include <hip/hip_runtime.h>
#include <math.h>

// Retinex MSR via GEMM: blur_s = G_s * X * G_s  (G_s symmetric Toeplitz blur).
// stage1: Y = X*G  (write Y^T fp16)   stage2: out += log(G*Y + 1)/3
// Then per-channel global min-max stretch.

#define NSL 48

// d_ws layout:
//   floats [0,4096): weights (padded) + minmax
#define W0_OFF 0      // sigma 15:  16 zero | 91 w | zeros   (alloc 512)
#define W1_OFF 512    // sigma 80:  16 zero | 481 w | zeros  (alloc 768)
#define W2_OFF 1280   // sigma 250: 16 zero | 1501 w | zeros (alloc 1536)
#define MM_OFF 2816   // 6 uints: min[3], max[3]
//   bytes  [16384, 16384+3*512*512*2): G16[3]
//   bytes  [1589248, +48*512*512*2):   T16 (Y^T per slice)
#define G16_BYTE_OFF 16384
#define T16_BYTE_OFF 1589248

typedef _Float16 half8 __attribute__((ext_vector_type(8)));
typedef _Float16 half4v __attribute__((ext_vector_type(4)));
typedef float f32x4 __attribute__((ext_vector_type(4)));

__device__ __forceinline__ void gload16(const void* g, void* l) {
  __builtin_amdgcn_global_load_lds(
      (const __attribute__((address_space(1))) void*)g,
      (__attribute__((address_space(3))) void*)l, 16, 0, 0);
}

// ---------------- weights ----------------
__global__ void wkern(float* __restrict__ ws) {
  __shared__ float red[256];
  const int s = blockIdx.x;
  const int Ks[3] = {91, 481, 1501};
  const float sg[3] = {15.f, 80.f, 250.f};
  const int off[3] = {W0_OFF, W1_OFF, W2_OFF};
  const int alloc[3] = {512, 768, 1536};
  const int K = Ks[s], A = alloc[s];
  float* wb = ws + off[s];
  const int t = threadIdx.x;
  for (int i = t; i < A; i += 256) wb[i] = 0.f;
  __syncthreads();
  const float inv2s2 = 1.f / (2.f * sg[s] * sg[s]);
  float part = 0.f;
  for (int i = t; i < K; i += 256) {
    const float d = (float)(i - K / 2);
    const float e = expf(-d * d * inv2s2);
    wb[16 + i] = e;
    part += e;
  }
  red[t] = part;
  __syncthreads();
  for (int st = 128; st > 0; st >>= 1) {
    if (t < st) red[t] += red[t + st];
    __syncthreads();
  }
  const float inv = 1.f / red[0];
  for (int i = t; i < K; i += 256) wb[16 + i] *= inv;
}

__global__ void mm_init(unsigned* __restrict__ mm) {
  const int t = threadIdx.x;
  if (t < 3) mm[t] = 0xFFFFFFFFu;
  else if (t < 6) mm[t] = 0u;
}

// ---------------- build G matrices (fp16) ----------------
__global__ void gkern(const float* __restrict__ ws, _Float16* __restrict__ gb) {
  const int y = blockIdx.x;
  const int s = blockIdx.y;
  const int Rs[3] = {45, 240, 750};
  const int off[3] = {W0_OFF, W1_OFF, W2_OFF};
  const float* w = ws + off[s] + 16;
  _Float16* g = gb + ((size_t)s << 18) + ((size_t)y << 9);
  const int R = Rs[s], K = 2 * R + 1;
  for (int x = threadIdx.x; x < 512; x += 256) {
    const int i = x - y + R;
    const float v = (i >= 0 && i < K) ? w[i] : 0.f;
    g[x] = (_Float16)v;
  }
}

// ---------------- batched 128x128-tile GEMM ----------------
// STAGE 1: D = X * G      A[m][c]=X (fp32, reg-staged->f16), B[c][n]=G
//          (B-LDS [n][c] <- G rows, valid since G symmetric); writes D^T to Tout.
// STAGE 2: D = G * Y      A[m][k]=G, B[k][n]=Y; B-LDS [n][k] <- Tin(=Y^T) rows.
//          out (+)= log(D+1)/3.
template <int STAGE, int R, bool FIRST>
__global__ __launch_bounds__(256) void gemm_k(const float* __restrict__ X,
                                              const _Float16* __restrict__ G,
                                              const _Float16* __restrict__ Tin,
                                              _Float16* __restrict__ Tout,
                                              float* __restrict__ out) {
  __shared__ __align__(16) _Float16 As[128 * 32];
  __shared__ __align__(16) _Float16 Bs[128 * 32];
  const int t = threadIdx.x;
  const int lane = t & 63;
  const int wave = t >> 6;
  const int wr = wave >> 1, wc = wave & 1;
  const int lr = lane & 15, lg = lane >> 4;
  const int bn = blockIdx.x << 7;
  const int bm = blockIdx.y << 7;
  const int slice = blockIdx.z;

  // K-band clip: the G operand is zero outside |k - tile| <= R
  const int cref = (STAGE == 1) ? bn : bm;
  int klo = cref - R;
  klo = (klo > 0 ? klo : 0) >> 5;
  int khi = cref + 127 + R;
  if (khi > 511) khi = 511;
  khi >>= 5;

  f32x4 acc[4][4];
#pragma unroll
  for (int i = 0; i < 4; ++i)
#pragma unroll
    for (int j = 0; j < 4; ++j) acc[i][j] = (f32x4){0.f, 0.f, 0.f, 0.f};

  for (int kt = klo; kt <= khi; ++kt) {
    const int k0 = kt << 5;
    __syncthreads();  // prev compute done before overwrite
#pragma unroll
    for (int q = 0; q < 2; ++q) {
      const int idx = (q << 8) + t;
      const int row = idx >> 2;
      const int c8 = (idx & 3) << 3;
      if (STAGE == 1) {
        const float* src = X + ((size_t)slice << 18) + ((size_t)(bm + row) << 9) + k0 + c8;
        const float4 v0 = *reinterpret_cast<const float4*>(src);
        const float4 v1 = *reinterpret_cast<const float4*>(src + 4);
        half8 hv;
        hv[0] = (_Float16)v0.x; hv[1] = (_Float16)v0.y;
        hv[2] = (_Float16)v0.z; hv[3] = (_Float16)v0.w;
        hv[4] = (_Float16)v1.x; hv[5] = (_Float16)v1.y;
        hv[6] = (_Float16)v1.z; hv[7] = (_Float16)v1.w;
        *reinterpret_cast<half8*>(&As[idx << 3]) = hv;
        gload16(G + ((size_t)(bn + row) << 9) + k0 + c8, &Bs[idx << 3]);
      } else {
        gload16(G + ((size_t)(bm + row) << 9) + k0 + c8, &As[idx << 3]);
        gload16(Tin + ((size_t)slice << 18) + ((size_t)(bn + row) << 9) + k0 + c8,
                &Bs[idx << 3]);
      }
    }
    __syncthreads();

    half8 af[4], bf[4];
#pragma unroll
    for (int f = 0; f < 4; ++f) {
      af[f] = *reinterpret_cast<const half8*>(
          &As[(((wr << 6) + (f << 4) + lr) << 5) + (lg << 3)]);
      bf[f] = *reinterpret_cast<const half8*>(
          &Bs[(((wc << 6) + (f << 4) + lr) << 5) + (lg << 3)]);
    }
#pragma unroll
    for (int fm = 0; fm < 4; ++fm)
#pragma unroll
      for (int fn = 0; fn < 4; ++fn)
        acc[fm][fn] = __builtin_amdgcn_mfma_f32_16x16x32_f16(af[fm], bf[fn],
                                                             acc[fm][fn], 0, 0, 0);
  }

  if (STAGE == 1) {
    // D[r][c]: c = lr (n), r = lg*4+j (X-row = final k). Write D^T: Tout[slice][n][k].
    _Float16* tdst = Tout + ((size_t)slice << 18);
#pragma unroll
    for (int fm = 0; fm < 4; ++fm)
#pragma unroll
      for (int fn = 0; fn < 4; ++fn) {
        const int n = bn + (wc << 6) + (fn << 4) + lr;
        const int rb = bm + (wr << 6) + (fm << 4) + (lg << 2);
        half4v h;
        h[0] = (_Float16)acc[fm][fn][0];
        h[1] = (_Float16)acc[fm][fn][1];
        h[2] = (_Float16)acc[fm][fn][2];
        h[3] = (_Float16)acc[fm][fn][3];
        *reinterpret_cast<half4v*>(&tdst[((size_t)n << 9) + rb]) = h;
      }
  } else {
    const float w3 = 1.f / 3.f;
#pragma unroll
    for (int fm = 0; fm < 4; ++fm)
#pragma unroll
      for (int fn = 0; fn < 4; ++fn) {
        const int rb = bm + (wr << 6) + (fm << 4) + (lg << 2);
        const int cg = bn + (wc << 6) + (fn << 4) + lr;
        float* op = out + ((size_t)slice << 18) + ((size_t)rb << 9) + cg;
#pragma unroll
        for (int j = 0; j < 4; ++j) {
          const float v = w3 * logf(acc[fm][fn][j] + 1.f);
          if (FIRST)
            op[j << 9] = v;
          else
            op[j << 9] += v;
        }
      }
  }
}

// ---------------- per-channel min/max + normalize ----------------
__global__ __launch_bounds__(256) void minmax_k(const float* __restrict__ r,
                                                unsigned* __restrict__ mm) {
  __shared__ float smn[256], smx[256];
  const int b = blockIdx.x;  // 768 = 48 slices * 16 pieces
  const int slice = b >> 4;
  const int piece = b & 15;
  const int ch = slice % 3;
  const float* p = r + ((size_t)slice << 18) + (piece << 14);
  const int t = threadIdx.x;
  float mn = 3.4e38f, mx = -3.4e38f;
  for (int q = 0; q < 16; ++q) {
    const float4 v = *reinterpret_cast<const float4*>(&p[(q * 256 + t) << 2]);
    mn = fminf(mn, fminf(fminf(v.x, v.y), fminf(v.z, v.w)));
    mx = fmaxf(mx, fmaxf(fmaxf(v.x, v.y), fmaxf(v.z, v.w)));
  }
  smn[t] = mn;
  smx[t] = mx;
  __syncthreads();
  for (int st = 128; st > 0; st >>= 1) {
    if (t < st) {
      smn[t] = fminf(smn[t], smn[t + st]);
      smx[t] = fmaxf(smx[t], smx[t + st]);
    }
    __syncthreads();
  }
  if (t == 0) {
    atomicMin(&mm[ch], __float_as_uint(smn[0]));  // values >= 0
    atomicMax(&mm[3 + ch], __float_as_uint(smx[0]));
  }
}

__global__ __launch_bounds__(256) void norm_k(float* __restrict__ r,
                                              const unsigned* __restrict__ mm) {
  const int b = blockIdx.x;
  const int slice = b >> 4;
  const int piece = b & 15;
  const int ch = slice % 3;
  const float mn = __uint_as_float(mm[ch]);
  const float mx = __uint_as_float(mm[3 + ch]);
  const float inv = 1.f / (mx - mn);
  float* p = r + ((size_t)slice << 18) + (piece << 14);
  const int t = threadIdx.x;
  for (int q = 0; q < 16; ++q) {
    float4 v = *reinterpret_cast<const float4*>(&p[(q * 256 + t) << 2]);
    v.x = (v.x - mn) * inv;
    v.y = (v.y - mn) * inv;
    v.z = (v.z - mn) * inv;
    v.w = (v.w - mn) * inv;
    *reinterpret_cast<float4*>(&p[(q * 256 + t) << 2]) = v;
  }
}

extern "C" void kernel_launch(void* const* d_in, const int* in_sizes, int n_in,
                              void* d_out, int out_size, void* d_ws, size_t ws_size,
                              hipStream_t stream) {
  const float* img = (const float*)d_in[0];
  float* out = (float*)d_out;
  float* wsf = (float*)d_ws;
  unsigned* mm = (unsigned*)(wsf + MM_OFF);
  _Float16* G16 = (_Float16*)((char*)d_ws + G16_BYTE_OFF);
  _Float16* T16 = (_Float16*)((char*)d_ws + T16_BYTE_OFF);

  wkern<<<3, 256, 0, stream>>>(wsf);
  mm_init<<<1, 64, 0, stream>>>(mm);
  gkern<<<dim3(512, 3), 256, 0, stream>>>(wsf, G16);

  dim3 gg(4, 4, NSL);
  // sigma 15
  gemm_k<1, 45, false><<<gg, 256, 0, stream>>>(img, G16, T16, T16, out);
  gemm_k<2, 45, true><<<gg, 256, 0, stream>>>(img, G16, T16, T16, out);
  // sigma 80
  gemm_k<1, 240, false><<<gg, 256, 0, stream>>>(img, G16 + (1 << 18), T16, T16, out);
  gemm_k<2, 240, false><<<gg, 256, 0, stream>>>(img, G16 + (1 << 18), T16, T16, out);
  // sigma 250
  gemm_k<1, 750, false><<<gg, 256, 0, stream>>>(img, G16 + (2 << 18), T16, T16, out);
  gemm_k<2, 750, false><<<gg, 256, 0, stream>>>(img, G16 + (2 << 18), T16, T16, out);

  minmax_k<<<768, 256, 0, stream>>>(out, mm);
  norm_k<<<768, 256, 0, stream>>>(out, mm);
}

// Round 4
// 179.751 us; speedup vs baseline: 5.9505x; 1.2432x over previous
//
#include <hip/hip_runtime.h>
#include <math.h>

// Retinex MSR via GEMM: blur_s = G_s * X * G_s  (G_s symmetric Toeplitz blur).
// xconv: X -> f16. gemm1 (z=144): Y_s^T = (X*G_s)^T  all sigmas.
// gemm2 (z=48):  out = sum_s log(G_s*Y_s + 1)/3, fused min/max reduction.
// norm: per-channel global min-max stretch.

#define NSL 48

// d_ws layout:
#define W0_OFF 0      // sigma 15:  16 zero | 91 w | zeros   (alloc 512 floats)
#define W1_OFF 512    // sigma 80:  16 zero | 481 w | zeros  (alloc 768)
#define W2_OFF 1280   // sigma 250: 16 zero | 1501 w | zeros (alloc 1536)
#define MM_OFF 2816   // 6 uints: min[3], max[3]
#define G16_BYTE_OFF 16384     // 3 * 512*512 f16   (1.5 MiB)
#define X16_BYTE_OFF 1589248   // 48 * 512*512 f16  (24 MiB)
#define T16_BYTE_OFF 26755072  // 3 * 48 * 512*512 f16 (72 MiB) -> total ~98 MiB < 256 MiB ws

typedef _Float16 half8 __attribute__((ext_vector_type(8)));
typedef _Float16 half4v __attribute__((ext_vector_type(4)));
typedef float f32x4 __attribute__((ext_vector_type(4)));

__device__ __forceinline__ void gload16(const void* g, void* l) {
  __builtin_amdgcn_global_load_lds(
      (const __attribute__((address_space(1))) void*)g,
      (__attribute__((address_space(3))) void*)l, 16, 0, 0);
}

// ---------------- weights ----------------
__global__ void wkern(float* __restrict__ ws) {
  __shared__ float red[256];
  const int s = blockIdx.x;
  const int Ks[3] = {91, 481, 1501};
  const float sg[3] = {15.f, 80.f, 250.f};
  const int off[3] = {W0_OFF, W1_OFF, W2_OFF};
  const int alloc[3] = {512, 768, 1536};
  const int K = Ks[s], A = alloc[s];
  float* wb = ws + off[s];
  const int t = threadIdx.x;
  for (int i = t; i < A; i += 256) wb[i] = 0.f;
  __syncthreads();
  const float inv2s2 = 1.f / (2.f * sg[s] * sg[s]);
  float part = 0.f;
  for (int i = t; i < K; i += 256) {
    const float d = (float)(i - K / 2);
    const float e = __expf(-d * d * inv2s2);
    wb[16 + i] = e;
    part += e;
  }
  red[t] = part;
  __syncthreads();
  for (int st = 128; st > 0; st >>= 1) {
    if (t < st) red[t] += red[t + st];
    __syncthreads();
  }
  const float inv = 1.f / red[0];
  for (int i = t; i < K; i += 256) wb[16 + i] *= inv;
}

__global__ void mm_init(unsigned* __restrict__ mm) {
  const int t = threadIdx.x;
  if (t < 3) mm[t] = 0xFFFFFFFFu;
  else if (t < 6) mm[t] = 0u;
}

// ---------------- build G matrices (fp16) ----------------
__global__ void gkern(const float* __restrict__ ws, _Float16* __restrict__ gb) {
  const int y = blockIdx.x;
  const int s = blockIdx.y;
  const int Rs[3] = {45, 240, 750};
  const int off[3] = {W0_OFF, W1_OFF, W2_OFF};
  const float* w = ws + off[s] + 16;
  _Float16* g = gb + ((size_t)s << 18) + ((size_t)y << 9);
  const int R = Rs[s], K = 2 * R + 1;
  for (int x = threadIdx.x; x < 512; x += 256) {
    const int i = x - y + R;
    const float v = (i >= 0 && i < K) ? w[i] : 0.f;
    g[x] = (_Float16)v;
  }
}

// ---------------- X fp32 -> fp16 ----------------
__global__ __launch_bounds__(256) void xconv(const float* __restrict__ X,
                                             _Float16* __restrict__ X16) {
  const size_t i = ((size_t)blockIdx.x * 256 + threadIdx.x) << 3;
  const float4 v0 = *reinterpret_cast<const float4*>(X + i);
  const float4 v1 = *reinterpret_cast<const float4*>(X + i + 4);
  half8 h;
  h[0] = (_Float16)v0.x; h[1] = (_Float16)v0.y;
  h[2] = (_Float16)v0.z; h[3] = (_Float16)v0.w;
  h[4] = (_Float16)v1.x; h[5] = (_Float16)v1.y;
  h[6] = (_Float16)v1.z; h[7] = (_Float16)v1.w;
  *reinterpret_cast<half8*>(X16 + i) = h;
}

// ---------------- stage 1: Y_s^T = (X * G_s)^T for all s, one dispatch ----------------
// A[m][c] = X16, B-LDS [n][c] <- G rows (G symmetric). Writes D^T.
__global__ __launch_bounds__(256) void gemm1_k(const _Float16* __restrict__ X16,
                                               const _Float16* __restrict__ G16,
                                               _Float16* __restrict__ T16) {
  __shared__ __align__(16) _Float16 As[128 * 32];
  __shared__ __align__(16) _Float16 Bs[128 * 32];
  const int t = threadIdx.x;
  const int lane = t & 63, wave = t >> 6;
  const int wr = wave >> 1, wc = wave & 1;
  const int lr = lane & 15, lg = lane >> 4;
  const int bn = blockIdx.x << 7;
  const int bm = blockIdx.y << 7;
  const int z = blockIdx.z;
  const int s = z / NSL;
  const int slice = z - s * NSL;
  const int Rs[3] = {45, 240, 750};
  const int R = Rs[s];
  const _Float16* Xp = X16 + ((size_t)slice << 18);
  const _Float16* G = G16 + ((size_t)s << 18);
  _Float16* Tout = T16 + (size_t)s * ((size_t)NSL << 18) + ((size_t)slice << 18);

  int klo = bn - R;
  klo = (klo > 0 ? klo : 0) >> 5;
  int khi = bn + 127 + R;
  if (khi > 511) khi = 511;
  khi >>= 5;

  f32x4 acc[4][4];
#pragma unroll
  for (int i = 0; i < 4; ++i)
#pragma unroll
    for (int j = 0; j < 4; ++j) acc[i][j] = (f32x4){0.f, 0.f, 0.f, 0.f};

  for (int kt = klo; kt <= khi; ++kt) {
    const int k0 = kt << 5;
    __syncthreads();
#pragma unroll
    for (int q = 0; q < 2; ++q) {
      const int idx = (q << 8) + t;
      const int row = idx >> 2;
      const int c8 = (idx & 3) << 3;
      gload16(Xp + ((size_t)(bm + row) << 9) + k0 + c8, &As[idx << 3]);
      gload16(G + ((size_t)(bn + row) << 9) + k0 + c8, &Bs[idx << 3]);
    }
    __syncthreads();

    half8 af[4], bf[4];
#pragma unroll
    for (int f = 0; f < 4; ++f) {
      af[f] = *reinterpret_cast<const half8*>(
          &As[(((wr << 6) + (f << 4) + lr) << 5) + (lg << 3)]);
      bf[f] = *reinterpret_cast<const half8*>(
          &Bs[(((wc << 6) + (f << 4) + lr) << 5) + (lg << 3)]);
    }
#pragma unroll
    for (int fm = 0; fm < 4; ++fm)
#pragma unroll
      for (int fn = 0; fn < 4; ++fn)
        acc[fm][fn] = __builtin_amdgcn_mfma_f32_16x16x32_f16(af[fm], bf[fn],
                                                             acc[fm][fn], 0, 0, 0);
  }

  // D[r][c]: c = n (lane lr), r = lg*4+j. Write D^T: Tout[n][k].
#pragma unroll
  for (int fm = 0; fm < 4; ++fm)
#pragma unroll
    for (int fn = 0; fn < 4; ++fn) {
      const int n = bn + (wc << 6) + (fn << 4) + lr;
      const int rb = bm + (wr << 6) + (fm << 4) + (lg << 2);
      half4v h;
      h[0] = (_Float16)acc[fm][fn][0];
      h[1] = (_Float16)acc[fm][fn][1];
      h[2] = (_Float16)acc[fm][fn][2];
      h[3] = (_Float16)acc[fm][fn][3];
      *reinterpret_cast<half4v*>(&Tout[((size_t)n << 9) + rb]) = h;
    }
}

// ---------------- stage 2 fused: out = sum_s log(G_s*Y_s + 1)/3, + min/max ----------------
__global__ __launch_bounds__(256) void gemm2_k(const _Float16* __restrict__ G16,
                                               const _Float16* __restrict__ T16,
                                               float* __restrict__ out,
                                               unsigned* __restrict__ mm) {
  __shared__ __align__(16) _Float16 As[128 * 32];
  __shared__ __align__(16) _Float16 Bs[128 * 32];
  __shared__ float smn[4], smx[4];
  const int t = threadIdx.x;
  const int lane = t & 63, wave = t >> 6;
  const int wr = wave >> 1, wc = wave & 1;
  const int lr = lane & 15, lg = lane >> 4;
  const int bn = blockIdx.x << 7;
  const int bm = blockIdx.y << 7;
  const int slice = blockIdx.z;
  const float w3 = 1.f / 3.f;
  const int Rs[3] = {45, 240, 750};

  f32x4 res[4][4];
#pragma unroll
  for (int i = 0; i < 4; ++i)
#pragma unroll
    for (int j = 0; j < 4; ++j) res[i][j] = (f32x4){0.f, 0.f, 0.f, 0.f};

#pragma unroll 1
  for (int s = 0; s < 3; ++s) {
    const int R = Rs[s];
    const _Float16* G = G16 + ((size_t)s << 18);
    const _Float16* T = T16 + (size_t)s * ((size_t)NSL << 18) + ((size_t)slice << 18);
    int klo = bm - R;
    klo = (klo > 0 ? klo : 0) >> 5;
    int khi = bm + 127 + R;
    if (khi > 511) khi = 511;
    khi >>= 5;

    f32x4 acc[4][4];
#pragma unroll
    for (int i = 0; i < 4; ++i)
#pragma unroll
      for (int j = 0; j < 4; ++j) acc[i][j] = (f32x4){0.f, 0.f, 0.f, 0.f};

    for (int kt = klo; kt <= khi; ++kt) {
      const int k0 = kt << 5;
      __syncthreads();
#pragma unroll
      for (int q = 0; q < 2; ++q) {
        const int idx = (q << 8) + t;
        const int row = idx >> 2;
        const int c8 = (idx & 3) << 3;
        gload16(G + ((size_t)(bm + row) << 9) + k0 + c8, &As[idx << 3]);
        gload16(T + ((size_t)(bn + row) << 9) + k0 + c8, &Bs[idx << 3]);
      }
      __syncthreads();

      half8 af[4], bf[4];
#pragma unroll
      for (int f = 0; f < 4; ++f) {
        af[f] = *reinterpret_cast<const half8*>(
            &As[(((wr << 6) + (f << 4) + lr) << 5) + (lg << 3)]);
        bf[f] = *reinterpret_cast<const half8*>(
            &Bs[(((wc << 6) + (f << 4) + lr) << 5) + (lg << 3)]);
      }
#pragma unroll
      for (int fm = 0; fm < 4; ++fm)
#pragma unroll
        for (int fn = 0; fn < 4; ++fn)
          acc[fm][fn] = __builtin_amdgcn_mfma_f32_16x16x32_f16(af[fm], bf[fn],
                                                               acc[fm][fn], 0, 0, 0);
    }

#pragma unroll
    for (int fm = 0; fm < 4; ++fm)
#pragma unroll
      for (int fn = 0; fn < 4; ++fn)
#pragma unroll
        for (int j = 0; j < 4; ++j)
          res[fm][fn][j] += w3 * __logf(acc[fm][fn][j] + 1.f);
  }

  // write out + per-thread min/max
  float mn = 3.4e38f, mx = -3.4e38f;
#pragma unroll
  for (int fm = 0; fm < 4; ++fm)
#pragma unroll
    for (int fn = 0; fn < 4; ++fn) {
      const int rb = bm + (wr << 6) + (fm << 4) + (lg << 2);
      const int cg = bn + (wc << 6) + (fn << 4) + lr;
      float* op = out + ((size_t)slice << 18) + ((size_t)rb << 9) + cg;
#pragma unroll
      for (int j = 0; j < 4; ++j) {
        const float v = res[fm][fn][j];
        op[j << 9] = v;
        mn = fminf(mn, v);
        mx = fmaxf(mx, v);
      }
    }
#pragma unroll
  for (int off = 32; off > 0; off >>= 1) {
    mn = fminf(mn, __shfl_xor(mn, off));
    mx = fmaxf(mx, __shfl_xor(mx, off));
  }
  if (lane == 0) {
    smn[wave] = mn;
    smx[wave] = mx;
  }
  __syncthreads();
  if (t == 0) {
    mn = fminf(fminf(smn[0], smn[1]), fminf(smn[2], smn[3]));
    mx = fmaxf(fmaxf(smx[0], smx[1]), fmaxf(smx[2], smx[3]));
    const int ch = slice % 3;
    atomicMin(&mm[ch], __float_as_uint(mn));  // values >= 0
    atomicMax(&mm[3 + ch], __float_as_uint(mx));
  }
}

// ---------------- normalize ----------------
__global__ __launch_bounds__(256) void norm_k(float* __restrict__ r,
                                              const unsigned* __restrict__ mm) {
  const int b = blockIdx.x;
  const int slice = b >> 4;
  const int piece = b & 15;
  const int ch = slice % 3;
  const float mn = __uint_as_float(mm[ch]);
  const float mx = __uint_as_float(mm[3 + ch]);
  const float inv = 1.f / (mx - mn);
  float* p = r + ((size_t)slice << 18) + (piece << 14);
  const int t = threadIdx.x;
  for (int q = 0; q < 16; ++q) {
    float4 v = *reinterpret_cast<const float4*>(&p[(q * 256 + t) << 2]);
    v.x = (v.x - mn) * inv;
    v.y = (v.y - mn) * inv;
    v.z = (v.z - mn) * inv;
    v.w = (v.w - mn) * inv;
    *reinterpret_cast<float4*>(&p[(q * 256 + t) << 2]) = v;
  }
}

extern "C" void kernel_launch(void* const* d_in, const int* in_sizes, int n_in,
                              void* d_out, int out_size, void* d_ws, size_t ws_size,
                              hipStream_t stream) {
  const float* img = (const float*)d_in[0];
  float* out = (float*)d_out;
  float* wsf = (float*)d_ws;
  unsigned* mm = (unsigned*)(wsf + MM_OFF);
  _Float16* G16 = (_Float16*)((char*)d_ws + G16_BYTE_OFF);
  _Float16* X16 = (_Float16*)((char*)d_ws + X16_BYTE_OFF);
  _Float16* T16 = (_Float16*)((char*)d_ws + T16_BYTE_OFF);

  wkern<<<3, 256, 0, stream>>>(wsf);
  mm_init<<<1, 64, 0, stream>>>(mm);
  gkern<<<dim3(512, 3), 256, 0, stream>>>(wsf, G16);
  xconv<<<6144, 256, 0, stream>>>(img, X16);

  gemm1_k<<<dim3(4, 4, 3 * NSL), 256, 0, stream>>>(X16, G16, T16);
  gemm2_k<<<dim3(4, 4, NSL), 256, 0, stream>>>(G16, T16, out, mm);

  norm_k<<<768, 256, 0, stream>>>(out, mm);
}

// Round 6
// 163.169 us; speedup vs baseline: 6.5552x; 1.1016x over previous
//
#include <hip/hip_runtime.h>
#include <math.h>

// Retinex MSR via GEMM: blur_s = G_s * X * G_s  (G_s symmetric Toeplitz blur).
// xconv: X -> f16. gemm1 (z=144): Ys^T[a][b] = sum_k G_s[a][k] X[b][k].
// gemm2 (z=48):  out = sum_s log(G_s*Y_s + 1)/3, fused min/max reduction.
// Both GEMMs: 128x128 tile, BK=32, double-buffered LDS, ONE barrier per K-step.
// norm: per-channel global min-max stretch.

#define NSL 48

// d_ws layout:
#define W0_OFF 0      // sigma 15:  16 zero | 91 w | zeros   (alloc 512 floats)
#define W1_OFF 512    // sigma 80:  16 zero | 481 w | zeros  (alloc 768)
#define W2_OFF 1280   // sigma 250: 16 zero | 1501 w | zeros (alloc 1536)
#define MM_OFF 2816   // 6 uints: min[3], max[3]
#define G16_BYTE_OFF 16384     // 3 * 512*512 f16   (1.5 MiB)
#define X16_BYTE_OFF 1589248   // 48 * 512*512 f16  (24 MiB)
#define T16_BYTE_OFF 26755072  // 3 * 48 * 512*512 f16 (72 MiB)

typedef _Float16 half8 __attribute__((ext_vector_type(8)));
typedef float f32x4 __attribute__((ext_vector_type(4)));

__device__ __forceinline__ void gload16(const void* g, void* l) {
  __builtin_amdgcn_global_load_lds(
      (const __attribute__((address_space(1))) void*)g,
      (__attribute__((address_space(3))) void*)l, 16, 0, 0);
}

// ---------------- weights ----------------
__global__ void wkern(float* __restrict__ ws) {
  __shared__ float red[256];
  const int s = blockIdx.x;
  const int Ks[3] = {91, 481, 1501};
  const float sg[3] = {15.f, 80.f, 250.f};
  const int off[3] = {W0_OFF, W1_OFF, W2_OFF};
  const int alloc[3] = {512, 768, 1536};
  const int K = Ks[s], A = alloc[s];
  float* wb = ws + off[s];
  const int t = threadIdx.x;
  for (int i = t; i < A; i += 256) wb[i] = 0.f;
  __syncthreads();
  const float inv2s2 = 1.f / (2.f * sg[s] * sg[s]);
  float part = 0.f;
  for (int i = t; i < K; i += 256) {
    const float d = (float)(i - K / 2);
    const float e = __expf(-d * d * inv2s2);
    wb[16 + i] = e;
    part += e;
  }
  red[t] = part;
  __syncthreads();
  for (int st = 128; st > 0; st >>= 1) {
    if (t < st) red[t] += red[t + st];
    __syncthreads();
  }
  const float inv = 1.f / red[0];
  for (int i = t; i < K; i += 256) wb[16 + i] *= inv;
}

__global__ void mm_init(unsigned* __restrict__ mm) {
  const int t = threadIdx.x;
  if (t < 3) mm[t] = 0xFFFFFFFFu;
  else if (t < 6) mm[t] = 0u;
}

// ---------------- build G matrices (fp16) ----------------
__global__ void gkern(const float* __restrict__ ws, _Float16* __restrict__ gb) {
  const int y = blockIdx.x;
  const int s = blockIdx.y;
  const int Rs[3] = {45, 240, 750};
  const int off[3] = {W0_OFF, W1_OFF, W2_OFF};
  const float* w = ws + off[s] + 16;
  _Float16* g = gb + ((size_t)s << 18) + ((size_t)y << 9);
  const int R = Rs[s], K = 2 * R + 1;
  for (int x = threadIdx.x; x < 512; x += 256) {
    const int i = x - y + R;
    const float v = (i >= 0 && i < K) ? w[i] : 0.f;
    g[x] = (_Float16)v;
  }
}

// ---------------- X fp32 -> fp16 ----------------
__global__ __launch_bounds__(256) void xconv(const float* __restrict__ X,
                                             _Float16* __restrict__ X16) {
  const size_t i = ((size_t)blockIdx.x * 256 + threadIdx.x) << 3;
  const float4 v0 = *reinterpret_cast<const float4*>(X + i);
  const float4 v1 = *reinterpret_cast<const float4*>(X + i + 4);
  half8 h;
  h[0] = (_Float16)v0.x; h[1] = (_Float16)v0.y;
  h[2] = (_Float16)v0.z; h[3] = (_Float16)v0.w;
  h[4] = (_Float16)v1.x; h[5] = (_Float16)v1.y;
  h[6] = (_Float16)v1.z; h[7] = (_Float16)v1.w;
  *reinterpret_cast<half8*>(X16 + i) = h;
}

// stage helper: stage A-rows (bm tile) and B-rows (bn tile) for K-tile k0 into buf
#define STAGE(buf, k0)                                                              \
  do {                                                                              \
    _Pragma("unroll") for (int q = 0; q < 2; ++q) {                                 \
      const int idx = (q << 8) + t;                                                 \
      const int row = idx >> 2;                                                     \
      const int c8 = (idx & 3) << 3;                                                \
      gload16(Ap + ((size_t)(bm + row) << 9) + (k0) + c8, &As[buf][idx << 3]);      \
      gload16(Bp + ((size_t)(bn + row) << 9) + (k0) + c8, &Bs[buf][idx << 3]);      \
    }                                                                               \
  } while (0)

#define FRAGS_AND_MFMA(buf)                                                         \
  do {                                                                              \
    half8 af[4], bf[4];                                                             \
    _Pragma("unroll") for (int f = 0; f < 4; ++f) {                                 \
      af[f] = *reinterpret_cast<const half8*>(                                      \
          &As[buf][(((wr << 6) + (f << 4) + lr) << 5) + (lg << 3)]);                \
      bf[f] = *reinterpret_cast<const half8*>(                                      \
          &Bs[buf][(((wc << 6) + (f << 4) + lr) << 5) + (lg << 3)]);                \
    }                                                                               \
    _Pragma("unroll") for (int fm = 0; fm < 4; ++fm)                                \
        _Pragma("unroll") for (int fn = 0; fn < 4; ++fn)                            \
        acc[fm][fn] = __builtin_amdgcn_mfma_f32_16x16x32_f16(af[fm], bf[fn],        \
                                                             acc[fm][fn], 0, 0, 0); \
  } while (0)

// ---------------- stage 1: Ys^T = G_s * X^T (via B=X rows), one dispatch all s ----------------
__global__ __launch_bounds__(256) void gemm1_k(const _Float16* __restrict__ X16,
                                               const _Float16* __restrict__ G16,
                                               _Float16* __restrict__ T16) {
  __shared__ __align__(16) _Float16 As[2][128 * 32];
  __shared__ __align__(16) _Float16 Bs[2][128 * 32];
  const int t = threadIdx.x;
  const int lane = t & 63, wave = t >> 6;
  const int wr = wave >> 1, wc = wave & 1;
  const int lr = lane & 15, lg = lane >> 4;
  const int bn = blockIdx.x << 7;
  const int bm = blockIdx.y << 7;
  const int z = blockIdx.z;
  const int s = z / NSL;
  const int slice = z - s * NSL;
  const int Rs[3] = {45, 240, 750};
  const int R = Rs[s];
  const _Float16* Ap = G16 + ((size_t)s << 18);           // A = G_s (bm rows, band clip)
  const _Float16* Bp = X16 + ((size_t)slice << 18);       // B = X rows
  _Float16* Tout = T16 + ((size_t)z << 18);               // Tout[a][b] = Ys^T

  int klo = bm - R;
  klo = (klo > 0 ? klo : 0) >> 5;
  int khi = bm + 127 + R;
  if (khi > 511) khi = 511;
  khi >>= 5;

  f32x4 acc[4][4];
#pragma unroll
  for (int i = 0; i < 4; ++i)
#pragma unroll
    for (int j = 0; j < 4; ++j) acc[i][j] = (f32x4){0.f, 0.f, 0.f, 0.f};

  int cur = 0;
  STAGE(0, klo << 5);
  __syncthreads();
  for (int kt = klo; kt <= khi; ++kt) {
    if (kt < khi) STAGE(cur ^ 1, (kt + 1) << 5);
    FRAGS_AND_MFMA(cur);
    __syncthreads();
    cur ^= 1;
  }

  // D[a][b]: a = bm+wr*64+fm*16+lg*4+j, b = bn+wc*64+fn*16+lr. Row-major, coalesced runs.
#pragma unroll
  for (int fm = 0; fm < 4; ++fm)
#pragma unroll
    for (int fn = 0; fn < 4; ++fn) {
      const int a0 = bm + (wr << 6) + (fm << 4) + (lg << 2);
      const int b0 = bn + (wc << 6) + (fn << 4) + lr;
#pragma unroll
      for (int j = 0; j < 4; ++j)
        Tout[((size_t)(a0 + j) << 9) + b0] = (_Float16)acc[fm][fn][j];
    }
}

// ---------------- stage 2 fused: out = sum_s log(G_s*Y_s + 1)/3, + min/max ----------------
__global__ __launch_bounds__(256) void gemm2_k(const _Float16* __restrict__ G16,
                                               const _Float16* __restrict__ T16,
                                               float* __restrict__ out,
                                               unsigned* __restrict__ mm) {
  __shared__ __align__(16) _Float16 As[2][128 * 32];
  __shared__ __align__(16) _Float16 Bs[2][128 * 32];
  __shared__ float smn[4], smx[4];
  const int t = threadIdx.x;
  const int lane = t & 63, wave = t >> 6;
  const int wr = wave >> 1, wc = wave & 1;
  const int lr = lane & 15, lg = lane >> 4;
  const int bn = blockIdx.x << 7;
  const int bm = blockIdx.y << 7;
  const int slice = blockIdx.z;
  const float w3 = 1.f / 3.f;
  const int Rs[3] = {45, 240, 750};

  f32x4 res[4][4];
#pragma unroll
  for (int i = 0; i < 4; ++i)
#pragma unroll
    for (int j = 0; j < 4; ++j) res[i][j] = (f32x4){0.f, 0.f, 0.f, 0.f};

  int cur = 0;
#pragma unroll 1
  for (int s = 0; s < 3; ++s) {
    const int R = Rs[s];
    const _Float16* Ap = G16 + ((size_t)s << 18);
    const _Float16* Bp = T16 + ((size_t)(s * NSL + slice) << 18);
    int klo = bm - R;
    klo = (klo > 0 ? klo : 0) >> 5;
    int khi = bm + 127 + R;
    if (khi > 511) khi = 511;
    khi >>= 5;

    f32x4 acc[4][4];
#pragma unroll
    for (int i = 0; i < 4; ++i)
#pragma unroll
      for (int j = 0; j < 4; ++j) acc[i][j] = (f32x4){0.f, 0.f, 0.f, 0.f};

    STAGE(cur, klo << 5);
    __syncthreads();
    for (int kt = klo; kt <= khi; ++kt) {
      if (kt < khi) STAGE(cur ^ 1, (kt + 1) << 5);
      FRAGS_AND_MFMA(cur);
      __syncthreads();
      cur ^= 1;
    }

#pragma unroll
    for (int fm = 0; fm < 4; ++fm)
#pragma unroll
      for (int fn = 0; fn < 4; ++fn)
#pragma unroll
        for (int j = 0; j < 4; ++j)
          res[fm][fn][j] += w3 * __logf(acc[fm][fn][j] + 1.f);
  }

  // write out + fused per-channel min/max
  float mn = 3.4e38f, mx = -3.4e38f;
#pragma unroll
  for (int fm = 0; fm < 4; ++fm)
#pragma unroll
    for (int fn = 0; fn < 4; ++fn) {
      const int rb = bm + (wr << 6) + (fm << 4) + (lg << 2);
      const int cg = bn + (wc << 6) + (fn << 4) + lr;
      float* op = out + ((size_t)slice << 18) + ((size_t)rb << 9) + cg;
#pragma unroll
      for (int j = 0; j < 4; ++j) {
        const float v = res[fm][fn][j];
        op[j << 9] = v;
        mn = fminf(mn, v);
        mx = fmaxf(mx, v);
      }
    }
#pragma unroll
  for (int off = 32; off > 0; off >>= 1) {
    mn = fminf(mn, __shfl_xor(mn, off));
    mx = fmaxf(mx, __shfl_xor(mx, off));
  }
  if (lane == 0) {
    smn[wave] = mn;
    smx[wave] = mx;
  }
  __syncthreads();
  if (t == 0) {
    mn = fminf(fminf(smn[0], smn[1]), fminf(smn[2], smn[3]));
    mx = fmaxf(fmaxf(smx[0], smx[1]), fmaxf(smx[2], smx[3]));
    const int ch = slice % 3;
    atomicMin(&mm[ch], __float_as_uint(mn));  // values >= 0
    atomicMax(&mm[3 + ch], __float_as_uint(mx));
  }
}

// ---------------- normalize ----------------
__global__ __launch_bounds__(256) void norm_k(float* __restrict__ r,
                                              const unsigned* __restrict__ mm) {
  const int b = blockIdx.x;
  const int slice = b >> 4;
  const int piece = b & 15;
  const int ch = slice % 3;
  const float mn = __uint_as_float(mm[ch]);
  const float mx = __uint_as_float(mm[3 + ch]);
  const float inv = 1.f / (mx - mn);
  float* p = r + ((size_t)slice << 18) + (piece << 14);
  const int t = threadIdx.x;
  for (int q = 0; q < 16; ++q) {
    float4 v = *reinterpret_cast<const float4*>(&p[(q * 256 + t) << 2]);
    v.x = (v.x - mn) * inv;
    v.y = (v.y - mn) * inv;
    v.z = (v.z - mn) * inv;
    v.w = (v.w - mn) * inv;
    *reinterpret_cast<float4*>(&p[(q * 256 + t) << 2]) = v;
  }
}

extern "C" void kernel_launch(void* const* d_in, const int* in_sizes, int n_in,
                              void* d_out, int out_size, void* d_ws, size_t ws_size,
                              hipStream_t stream) {
  const float* img = (const float*)d_in[0];
  float* out = (float*)d_out;
  float* wsf = (float*)d_ws;
  unsigned* mm = (unsigned*)(wsf + MM_OFF);
  _Float16* G16 = (_Float16*)((char*)d_ws + G16_BYTE_OFF);
  _Float16* X16 = (_Float16*)((char*)d_ws + X16_BYTE_OFF);
  _Float16* T16 = (_Float16*)((char*)d_ws + T16_BYTE_OFF);

  wkern<<<3, 256, 0, stream>>>(wsf);
  mm_init<<<1, 64, 0, stream>>>(mm);
  gkern<<<dim3(512, 3), 256, 0, stream>>>(wsf, G16);
  xconv<<<6144, 256, 0, stream>>>(img, X16);

  gemm1_k<<<dim3(4, 4, 3 * NSL), 256, 0, stream>>>(X16, G16, T16);
  gemm2_k<<<dim3(4, 4, NSL), 256, 0, stream>>>(G16, T16, out, mm);

  norm_k<<<768, 256, 0, stream>>>(out, mm);
}

// Round 7
// 161.892 us; speedup vs baseline: 6.6069x; 1.0079x over previous
//
#include <hip/hip_runtime.h>
#include <math.h>

// Retinex MSR via GEMM: blur_s = G_s * X * G_s  (G_s symmetric Toeplitz blur).
// xconv: X -> f16. gemm1 (z=144): Ys^T[a][b] = sum_k G_s[a][k] X[b][k].
// gemm2 (z=48):  out = sum_s log(G_s*Y_s + 1)/3, fused min/max reduction.
// Both GEMMs: 128x128 tile, BK=32, THREE LDS buffers, counted vmcnt(4) + raw
// s_barrier per K-step (loads never drain mid-loop). norm: min-max stretch.

#define NSL 48

// d_ws layout:
#define W0_OFF 0      // sigma 15:  16 zero | 91 w | zeros   (alloc 512 floats)
#define W1_OFF 512    // sigma 80:  16 zero | 481 w | zeros  (alloc 768)
#define W2_OFF 1280   // sigma 250: 16 zero | 1501 w | zeros (alloc 1536)
#define MM_OFF 2816   // 6 uints: min[3], max[3]
#define G16_BYTE_OFF 16384     // 3 * 512*512 f16   (1.5 MiB)
#define X16_BYTE_OFF 1589248   // 48 * 512*512 f16  (24 MiB)
#define T16_BYTE_OFF 26755072  // 3 * 48 * 512*512 f16 (72 MiB)

typedef _Float16 half8 __attribute__((ext_vector_type(8)));
typedef float f32x4 __attribute__((ext_vector_type(4)));

__device__ __forceinline__ void gload16(const void* g, void* l) {
  __builtin_amdgcn_global_load_lds(
      (const __attribute__((address_space(1))) void*)g,
      (__attribute__((address_space(3))) void*)l, 16, 0, 0);
}

#define WAITV4() asm volatile("s_waitcnt vmcnt(4)" ::: "memory")
#define WAITV0() asm volatile("s_waitcnt vmcnt(0)" ::: "memory")
#define SCHEDB() __builtin_amdgcn_sched_barrier(0)
#define BARRIER() __builtin_amdgcn_s_barrier()

// ---------------- weights ----------------
__global__ void wkern(float* __restrict__ ws) {
  __shared__ float red[256];
  const int s = blockIdx.x;
  const int Ks[3] = {91, 481, 1501};
  const float sg[3] = {15.f, 80.f, 250.f};
  const int off[3] = {W0_OFF, W1_OFF, W2_OFF};
  const int alloc[3] = {512, 768, 1536};
  const int K = Ks[s], A = alloc[s];
  float* wb = ws + off[s];
  const int t = threadIdx.x;
  for (int i = t; i < A; i += 256) wb[i] = 0.f;
  __syncthreads();
  const float inv2s2 = 1.f / (2.f * sg[s] * sg[s]);
  float part = 0.f;
  for (int i = t; i < K; i += 256) {
    const float d = (float)(i - K / 2);
    const float e = __expf(-d * d * inv2s2);
    wb[16 + i] = e;
    part += e;
  }
  red[t] = part;
  __syncthreads();
  for (int st = 128; st > 0; st >>= 1) {
    if (t < st) red[t] += red[t + st];
    __syncthreads();
  }
  const float inv = 1.f / red[0];
  for (int i = t; i < K; i += 256) wb[16 + i] *= inv;
}

__global__ void mm_init(unsigned* __restrict__ mm) {
  const int t = threadIdx.x;
  if (t < 3) mm[t] = 0xFFFFFFFFu;
  else if (t < 6) mm[t] = 0u;
}

// ---------------- build G matrices (fp16) ----------------
__global__ void gkern(const float* __restrict__ ws, _Float16* __restrict__ gb) {
  const int y = blockIdx.x;
  const int s = blockIdx.y;
  const int Rs[3] = {45, 240, 750};
  const int off[3] = {W0_OFF, W1_OFF, W2_OFF};
  const float* w = ws + off[s] + 16;
  _Float16* g = gb + ((size_t)s << 18) + ((size_t)y << 9);
  const int R = Rs[s], K = 2 * R + 1;
  for (int x = threadIdx.x; x < 512; x += 256) {
    const int i = x - y + R;
    const float v = (i >= 0 && i < K) ? w[i] : 0.f;
    g[x] = (_Float16)v;
  }
}

// ---------------- X fp32 -> fp16 ----------------
__global__ __launch_bounds__(256) void xconv(const float* __restrict__ X,
                                             _Float16* __restrict__ X16) {
  const size_t i = ((size_t)blockIdx.x * 256 + threadIdx.x) << 3;
  const float4 v0 = *reinterpret_cast<const float4*>(X + i);
  const float4 v1 = *reinterpret_cast<const float4*>(X + i + 4);
  half8 h;
  h[0] = (_Float16)v0.x; h[1] = (_Float16)v0.y;
  h[2] = (_Float16)v0.z; h[3] = (_Float16)v0.w;
  h[4] = (_Float16)v1.x; h[5] = (_Float16)v1.y;
  h[6] = (_Float16)v1.z; h[7] = (_Float16)v1.w;
  *reinterpret_cast<half8*>(X16 + i) = h;
}

// stage helper: 4 gload16 per thread (2 A-rows + 2 B-rows chunks) for K-tile k0
#define STAGE(buf, k0)                                                              \
  do {                                                                              \
    _Pragma("unroll") for (int q = 0; q < 2; ++q) {                                 \
      const int idx = (q << 8) + t;                                                 \
      const int row = idx >> 2;                                                     \
      const int c8 = (idx & 3) << 3;                                                \
      gload16(Ap + ((size_t)(bm + row) << 9) + (k0) + c8, &As[buf][idx << 3]);      \
      gload16(Bp + ((size_t)(bn + row) << 9) + (k0) + c8, &Bs[buf][idx << 3]);      \
    }                                                                               \
  } while (0)

#define FRAGS_AND_MFMA(buf)                                                         \
  do {                                                                              \
    half8 af[4], bf[4];                                                             \
    _Pragma("unroll") for (int f = 0; f < 4; ++f) {                                 \
      af[f] = *reinterpret_cast<const half8*>(                                      \
          &As[buf][(((wr << 6) + (f << 4) + lr) << 5) + (lg << 3)]);                \
      bf[f] = *reinterpret_cast<const half8*>(                                      \
          &Bs[buf][(((wc << 6) + (f << 4) + lr) << 5) + (lg << 3)]);                \
    }                                                                               \
    _Pragma("unroll") for (int fm = 0; fm < 4; ++fm)                                \
        _Pragma("unroll") for (int fn = 0; fn < 4; ++fn)                            \
        acc[fm][fn] = __builtin_amdgcn_mfma_f32_16x16x32_f16(af[fm], bf[fn],        \
                                                             acc[fm][fn], 0, 0, 0); \
  } while (0)

// Pipelined K-loop: buffers cycle mod 3; one raw barrier + counted vmcnt per step.
// Safety: buf (cb+2)%3 was consumed in iter kt-1; all waves passed this iter's
// barrier => their iter kt-1 ds_reads completed. Write-visibility: each wave
// drains ITS OWN tile-kt loads via vmcnt before the shared barrier.
#define K_PIPELINE_LOOP()                                                           \
  do {                                                                              \
    STAGE(0, klo << 5);                                                             \
    STAGE(1, (klo + 1) << 5);                                                       \
    int cb = 0;                                                                     \
    for (int kt = klo; kt <= khi; ++kt) {                                           \
      if (kt < khi) { WAITV4(); } else { WAITV0(); }                                \
      SCHEDB();                                                                     \
      BARRIER();                                                                    \
      SCHEDB();                                                                     \
      if (kt + 2 <= khi) {                                                          \
        const int sb = (cb + 2 >= 3) ? cb - 1 : cb + 2;                             \
        STAGE(sb, (kt + 2) << 5);                                                   \
      }                                                                             \
      FRAGS_AND_MFMA(cb);                                                           \
      cb = (cb == 2) ? 0 : cb + 1;                                                  \
    }                                                                               \
  } while (0)

// ---------------- stage 1: Ys^T = G_s * X^T (B = X rows), one dispatch all s ----------------
__global__ __launch_bounds__(256) void gemm1_k(const _Float16* __restrict__ X16,
                                               const _Float16* __restrict__ G16,
                                               _Float16* __restrict__ T16) {
  __shared__ __align__(16) _Float16 As[3][128 * 32];
  __shared__ __align__(16) _Float16 Bs[3][128 * 32];
  const int t = threadIdx.x;
  const int lane = t & 63, wave = t >> 6;
  const int wr = wave >> 1, wc = wave & 1;
  const int lr = lane & 15, lg = lane >> 4;
  const int bn = blockIdx.x << 7;
  const int bm = blockIdx.y << 7;
  const int z = blockIdx.z;
  const int s = z / NSL;
  const int slice = z - s * NSL;
  const int Rs[3] = {45, 240, 750};
  const int R = Rs[s];
  const _Float16* Ap = G16 + ((size_t)s << 18);      // A = G_s (bm rows, band clip)
  const _Float16* Bp = X16 + ((size_t)slice << 18);  // B = X rows
  _Float16* Tout = T16 + ((size_t)z << 18);          // Tout[a][b] = Ys^T

  int klo = bm - R;
  klo = (klo > 0 ? klo : 0) >> 5;
  int khi = bm + 127 + R;
  if (khi > 511) khi = 511;
  khi >>= 5;

  f32x4 acc[4][4];
#pragma unroll
  for (int i = 0; i < 4; ++i)
#pragma unroll
    for (int j = 0; j < 4; ++j) acc[i][j] = (f32x4){0.f, 0.f, 0.f, 0.f};

  K_PIPELINE_LOOP();

  // D[a][b]: a = bm+wr*64+fm*16+lg*4+j, b = bn+wc*64+fn*16+lr. Row-major runs.
#pragma unroll
  for (int fm = 0; fm < 4; ++fm)
#pragma unroll
    for (int fn = 0; fn < 4; ++fn) {
      const int a0 = bm + (wr << 6) + (fm << 4) + (lg << 2);
      const int b0 = bn + (wc << 6) + (fn << 4) + lr;
#pragma unroll
      for (int j = 0; j < 4; ++j)
        Tout[((size_t)(a0 + j) << 9) + b0] = (_Float16)acc[fm][fn][j];
    }
}

// ---------------- stage 2 fused: out = sum_s log(G_s*Y_s + 1)/3, + min/max ----------------
__global__ __launch_bounds__(256) void gemm2_k(const _Float16* __restrict__ G16,
                                               const _Float16* __restrict__ T16,
                                               float* __restrict__ out,
                                               unsigned* __restrict__ mm) {
  __shared__ __align__(16) _Float16 As[3][128 * 32];
  __shared__ __align__(16) _Float16 Bs[3][128 * 32];
  __shared__ float smn[4], smx[4];
  const int t = threadIdx.x;
  const int lane = t & 63, wave = t >> 6;
  const int wr = wave >> 1, wc = wave & 1;
  const int lr = lane & 15, lg = lane >> 4;
  const int bn = blockIdx.x << 7;
  const int bm = blockIdx.y << 7;
  const int slice = blockIdx.z;
  const float w3 = 1.f / 3.f;
  const int Rs[3] = {45, 240, 750};

  f32x4 res[4][4];
#pragma unroll
  for (int i = 0; i < 4; ++i)
#pragma unroll
    for (int j = 0; j < 4; ++j) res[i][j] = (f32x4){0.f, 0.f, 0.f, 0.f};

#pragma unroll 1
  for (int s = 0; s < 3; ++s) {
    const int R = Rs[s];
    const _Float16* Ap = G16 + ((size_t)s << 18);
    const _Float16* Bp = T16 + ((size_t)(s * NSL + slice) << 18);
    int klo = bm - R;
    klo = (klo > 0 ? klo : 0) >> 5;
    int khi = bm + 127 + R;
    if (khi > 511) khi = 511;
    khi >>= 5;

    f32x4 acc[4][4];
#pragma unroll
    for (int i = 0; i < 4; ++i)
#pragma unroll
      for (int j = 0; j < 4; ++j) acc[i][j] = (f32x4){0.f, 0.f, 0.f, 0.f};

    BARRIER();  // protect buffers 0/1 from previous sigma's late readers
    K_PIPELINE_LOOP();

#pragma unroll
    for (int fm = 0; fm < 4; ++fm)
#pragma unroll
      for (int fn = 0; fn < 4; ++fn)
#pragma unroll
        for (int j = 0; j < 4; ++j)
          res[fm][fn][j] += w3 * __logf(acc[fm][fn][j] + 1.f);
  }

  // write out + fused per-channel min/max
  float mn = 3.4e38f, mx = -3.4e38f;
#pragma unroll
  for (int fm = 0; fm < 4; ++fm)
#pragma unroll
    for (int fn = 0; fn < 4; ++fn) {
      const int rb = bm + (wr << 6) + (fm << 4) + (lg << 2);
      const int cg = bn + (wc << 6) + (fn << 4) + lr;
      float* op = out + ((size_t)slice << 18) + ((size_t)rb << 9) + cg;
#pragma unroll
      for (int j = 0; j < 4; ++j) {
        const float v = res[fm][fn][j];
        op[j << 9] = v;
        mn = fminf(mn, v);
        mx = fmaxf(mx, v);
      }
    }
#pragma unroll
  for (int off = 32; off > 0; off >>= 1) {
    mn = fminf(mn, __shfl_xor(mn, off));
    mx = fmaxf(mx, __shfl_xor(mx, off));
  }
  if (lane == 0) {
    smn[wave] = mn;
    smx[wave] = mx;
  }
  __syncthreads();
  if (t == 0) {
    mn = fminf(fminf(smn[0], smn[1]), fminf(smn[2], smn[3]));
    mx = fmaxf(fmaxf(smx[0], smx[1]), fmaxf(smx[2], smx[3]));
    const int ch = slice % 3;
    atomicMin(&mm[ch], __float_as_uint(mn));  // values >= 0
    atomicMax(&mm[3 + ch], __float_as_uint(mx));
  }
}

// ---------------- normalize ----------------
__global__ __launch_bounds__(256) void norm_k(float* __restrict__ r,
                                              const unsigned* __restrict__ mm) {
  const int b = blockIdx.x;
  const int slice = b >> 4;
  const int piece = b & 15;
  const int ch = slice % 3;
  const float mn = __uint_as_float(mm[ch]);
  const float mx = __uint_as_float(mm[3 + ch]);
  const float inv = 1.f / (mx - mn);
  float* p = r + ((size_t)slice << 18) + (piece << 14);
  const int t = threadIdx.x;
  for (int q = 0; q < 16; ++q) {
    float4 v = *reinterpret_cast<const float4*>(&p[(q * 256 + t) << 2]);
    v.x = (v.x - mn) * inv;
    v.y = (v.y - mn) * inv;
    v.z = (v.z - mn) * inv;
    v.w = (v.w - mn) * inv;
    *reinterpret_cast<float4*>(&p[(q * 256 + t) << 2]) = v;
  }
}

extern "C" void kernel_launch(void* const* d_in, const int* in_sizes, int n_in,
                              void* d_out, int out_size, void* d_ws, size_t ws_size,
                              hipStream_t stream) {
  const float* img = (const float*)d_in[0];
  float* out = (float*)d_out;
  float* wsf = (float*)d_ws;
  unsigned* mm = (unsigned*)(wsf + MM_OFF);
  _Float16* G16 = (_Float16*)((char*)d_ws + G16_BYTE_OFF);
  _Float16* X16 = (_Float16*)((char*)d_ws + X16_BYTE_OFF);
  _Float16* T16 = (_Float16*)((char*)d_ws + T16_BYTE_OFF);

  wkern<<<3, 256, 0, stream>>>(wsf);
  mm_init<<<1, 64, 0, stream>>>(mm);
  gkern<<<dim3(512, 3), 256, 0, stream>>>(wsf, G16);
  xconv<<<6144, 256, 0, stream>>>(img, X16);

  gemm1_k<<<dim3(4, 4, 3 * NSL), 256, 0, stream>>>(X16, G16, T16);
  gemm2_k<<<dim3(4, 4, NSL), 256, 0, stream>>>(G16, T16, out, mm);

  norm_k<<<768, 256, 0, stream>>>(out, mm);
}

// Round 8
// 159.576 us; speedup vs baseline: 6.7028x; 1.0145x over previous
//
#include <hip/hip_runtime.h>
#include <math.h>

// Retinex MSR via GEMM: blur_s = G_s * X * G_s  (G_s symmetric Toeplitz blur).
// xconv: X -> f16. gemm1 (z=144): Ys^T[a][b] = sum_k G_s[a][k] X[b][k].
// gemm2 (z=48):  out = sum_s log(G_s*Y_s + 1)/3, fused min/max reduction.
// Both GEMMs: 128x128 tile, BK=32, THREE LDS buffers, counted vmcnt(4) + raw
// s_barrier per K-step; staging uses incremented per-thread pointers (no
// per-step 64-bit addr recompute). norm: min-max stretch.

#define NSL 48

// d_ws layout:
#define W0_OFF 0      // sigma 15:  16 zero | 91 w | zeros   (alloc 512 floats)
#define W1_OFF 512    // sigma 80:  16 zero | 481 w | zeros  (alloc 768)
#define W2_OFF 1280   // sigma 250: 16 zero | 1501 w | zeros (alloc 1536)
#define MM_OFF 2816   // 6 uints: min[3], max[3]
#define G16_BYTE_OFF 16384     // 3 * 512*512 f16   (1.5 MiB)
#define X16_BYTE_OFF 1589248   // 48 * 512*512 f16  (24 MiB)
#define T16_BYTE_OFF 26755072  // 3 * 48 * 512*512 f16 (72 MiB)

typedef _Float16 half8 __attribute__((ext_vector_type(8)));
typedef float f32x4 __attribute__((ext_vector_type(4)));

__device__ __forceinline__ void gload16(const void* g, void* l) {
  __builtin_amdgcn_global_load_lds(
      (const __attribute__((address_space(1))) void*)g,
      (__attribute__((address_space(3))) void*)l, 16, 0, 0);
}

#define WAITV4() asm volatile("s_waitcnt vmcnt(4)" ::: "memory")
#define WAITV0() asm volatile("s_waitcnt vmcnt(0)" ::: "memory")
#define SCHEDB() __builtin_amdgcn_sched_barrier(0)
#define BARRIER() __builtin_amdgcn_s_barrier()

// ---------------- weights ----------------
__global__ void wkern(float* __restrict__ ws) {
  __shared__ float red[256];
  const int s = blockIdx.x;
  const int Ks[3] = {91, 481, 1501};
  const float sg[3] = {15.f, 80.f, 250.f};
  const int off[3] = {W0_OFF, W1_OFF, W2_OFF};
  const int alloc[3] = {512, 768, 1536};
  const int K = Ks[s], A = alloc[s];
  float* wb = ws + off[s];
  const int t = threadIdx.x;
  for (int i = t; i < A; i += 256) wb[i] = 0.f;
  __syncthreads();
  const float inv2s2 = 1.f / (2.f * sg[s] * sg[s]);
  float part = 0.f;
  for (int i = t; i < K; i += 256) {
    const float d = (float)(i - K / 2);
    const float e = __expf(-d * d * inv2s2);
    wb[16 + i] = e;
    part += e;
  }
  red[t] = part;
  __syncthreads();
  for (int st = 128; st > 0; st >>= 1) {
    if (t < st) red[t] += red[t + st];
    __syncthreads();
  }
  const float inv = 1.f / red[0];
  for (int i = t; i < K; i += 256) wb[16 + i] *= inv;
}

__global__ void mm_init(unsigned* __restrict__ mm) {
  const int t = threadIdx.x;
  if (t < 3) mm[t] = 0xFFFFFFFFu;
  else if (t < 6) mm[t] = 0u;
}

// ---------------- build G matrices (fp16) ----------------
__global__ void gkern(const float* __restrict__ ws, _Float16* __restrict__ gb) {
  const int y = blockIdx.x;
  const int s = blockIdx.y;
  const int Rs[3] = {45, 240, 750};
  const int off[3] = {W0_OFF, W1_OFF, W2_OFF};
  const float* w = ws + off[s] + 16;
  _Float16* g = gb + ((size_t)s << 18) + ((size_t)y << 9);
  const int R = Rs[s], K = 2 * R + 1;
  for (int x = threadIdx.x; x < 512; x += 256) {
    const int i = x - y + R;
    const float v = (i >= 0 && i < K) ? w[i] : 0.f;
    g[x] = (_Float16)v;
  }
}

// ---------------- X fp32 -> fp16 ----------------
__global__ __launch_bounds__(256) void xconv(const float* __restrict__ X,
                                             _Float16* __restrict__ X16) {
  const size_t i = ((size_t)blockIdx.x * 256 + threadIdx.x) << 3;
  const float4 v0 = *reinterpret_cast<const float4*>(X + i);
  const float4 v1 = *reinterpret_cast<const float4*>(X + i + 4);
  half8 h;
  h[0] = (_Float16)v0.x; h[1] = (_Float16)v0.y;
  h[2] = (_Float16)v0.z; h[3] = (_Float16)v0.w;
  h[4] = (_Float16)v1.x; h[5] = (_Float16)v1.y;
  h[6] = (_Float16)v1.z; h[7] = (_Float16)v1.w;
  *reinterpret_cast<half8*>(X16 + i) = h;
}

// stage via pre-computed per-thread pointers; advance by BK (32 elems) after.
#define STAGE_P(buf)                                 \
  do {                                               \
    gload16(pA0, &As[buf][t << 3]);                  \
    gload16(pA1, &As[buf][(256 + t) << 3]);          \
    gload16(pB0, &Bs[buf][t << 3]);                  \
    gload16(pB1, &Bs[buf][(256 + t) << 3]);          \
    pA0 += 32; pA1 += 32; pB0 += 32; pB1 += 32;      \
  } while (0)

#define FRAGS_AND_MFMA(buf)                                                         \
  do {                                                                              \
    half8 af[4], bf[4];                                                             \
    _Pragma("unroll") for (int f = 0; f < 4; ++f) {                                 \
      af[f] = *reinterpret_cast<const half8*>(                                      \
          &As[buf][(((wr << 6) + (f << 4) + lr) << 5) + (lg << 3)]);                \
      bf[f] = *reinterpret_cast<const half8*>(                                      \
          &Bs[buf][(((wc << 6) + (f << 4) + lr) << 5) + (lg << 3)]);                \
    }                                                                               \
    _Pragma("unroll") for (int fm = 0; fm < 4; ++fm)                                \
        _Pragma("unroll") for (int fn = 0; fn < 4; ++fn)                            \
        acc[fm][fn] = __builtin_amdgcn_mfma_f32_16x16x32_f16(af[fm], bf[fn],        \
                                                             acc[fm][fn], 0, 0, 0); \
  } while (0)

// Pipelined K-loop: buffers cycle mod 3; one raw barrier + counted vmcnt per step.
// Safety: buf (cb+2)%3 was consumed in iter kt-1; all waves passed this iter's
// barrier => their iter kt-1 ds_reads completed. Write-visibility: each wave
// drains ITS OWN tile loads via vmcnt before the shared barrier.
#define K_PIPELINE_LOOP()                                                           \
  do {                                                                              \
    const int row_ = t >> 2;                                                        \
    const int c8_ = (t & 3) << 3;                                                   \
    const _Float16* pA0 =                                                           \
        Ap + ((size_t)(bm + row_) << 9) + (klo << 5) + c8_;                         \
    const _Float16* pA1 = pA0 + ((size_t)64 << 9);                                  \
    const _Float16* pB0 =                                                           \
        Bp + ((size_t)(bn + row_) << 9) + (klo << 5) + c8_;                         \
    const _Float16* pB1 = pB0 + ((size_t)64 << 9);                                  \
    STAGE_P(0);                                                                     \
    STAGE_P(1);                                                                     \
    int cb = 0;                                                                     \
    for (int kt = klo; kt <= khi; ++kt) {                                           \
      if (kt < khi) { WAITV4(); } else { WAITV0(); }                                \
      SCHEDB();                                                                     \
      BARRIER();                                                                    \
      SCHEDB();                                                                     \
      if (kt + 2 <= khi) {                                                          \
        const int sb = (cb + 2 >= 3) ? cb - 1 : cb + 2;                             \
        STAGE_P(sb);                                                                \
      }                                                                             \
      FRAGS_AND_MFMA(cb);                                                           \
      cb = (cb == 2) ? 0 : cb + 1;                                                  \
    }                                                                               \
  } while (0)

// ---------------- stage 1: Ys^T = G_s * X^T (B = X rows), one dispatch all s ----------------
__global__ __launch_bounds__(256) void gemm1_k(const _Float16* __restrict__ X16,
                                               const _Float16* __restrict__ G16,
                                               _Float16* __restrict__ T16) {
  __shared__ __align__(16) _Float16 As[3][128 * 32];
  __shared__ __align__(16) _Float16 Bs[3][128 * 32];
  const int t = threadIdx.x;
  const int lane = t & 63, wave = t >> 6;
  const int wr = wave >> 1, wc = wave & 1;
  const int lr = lane & 15, lg = lane >> 4;
  const int bn = blockIdx.x << 7;
  const int bm = blockIdx.y << 7;
  const int z = blockIdx.z;
  const int s = z / NSL;
  const int slice = z - s * NSL;
  const int Rs[3] = {45, 240, 750};
  const int R = Rs[s];
  const _Float16* Ap = G16 + ((size_t)s << 18);      // A = G_s (bm rows, band clip)
  const _Float16* Bp = X16 + ((size_t)slice << 18);  // B = X rows
  _Float16* Tout = T16 + ((size_t)z << 18);          // Tout[a][b] = Ys^T

  int klo = bm - R;
  klo = (klo > 0 ? klo : 0) >> 5;
  int khi = bm + 127 + R;
  if (khi > 511) khi = 511;
  khi >>= 5;

  f32x4 acc[4][4];
#pragma unroll
  for (int i = 0; i < 4; ++i)
#pragma unroll
    for (int j = 0; j < 4; ++j) acc[i][j] = (f32x4){0.f, 0.f, 0.f, 0.f};

  K_PIPELINE_LOOP();

  // D[a][b]: a = bm+wr*64+fm*16+lg*4+j, b = bn+wc*64+fn*16+lr. Row-major runs.
#pragma unroll
  for (int fm = 0; fm < 4; ++fm)
#pragma unroll
    for (int fn = 0; fn < 4; ++fn) {
      const int a0 = bm + (wr << 6) + (fm << 4) + (lg << 2);
      const int b0 = bn + (wc << 6) + (fn << 4) + lr;
#pragma unroll
      for (int j = 0; j < 4; ++j)
        Tout[((size_t)(a0 + j) << 9) + b0] = (_Float16)acc[fm][fn][j];
    }
}

// ---------------- stage 2 fused: out = sum_s log(G_s*Y_s + 1)/3, + min/max ----------------
__global__ __launch_bounds__(256) void gemm2_k(const _Float16* __restrict__ G16,
                                               const _Float16* __restrict__ T16,
                                               float* __restrict__ out,
                                               unsigned* __restrict__ mm) {
  __shared__ __align__(16) _Float16 As[3][128 * 32];
  __shared__ __align__(16) _Float16 Bs[3][128 * 32];
  __shared__ float smn[4], smx[4];
  const int t = threadIdx.x;
  const int lane = t & 63, wave = t >> 6;
  const int wr = wave >> 1, wc = wave & 1;
  const int lr = lane & 15, lg = lane >> 4;
  const int bn = blockIdx.x << 7;
  const int bm = blockIdx.y << 7;
  const int slice = blockIdx.z;
  const float w3 = 1.f / 3.f;
  const int Rs[3] = {45, 240, 750};

  f32x4 res[4][4];
#pragma unroll
  for (int i = 0; i < 4; ++i)
#pragma unroll
    for (int j = 0; j < 4; ++j) res[i][j] = (f32x4){0.f, 0.f, 0.f, 0.f};

#pragma unroll 1
  for (int s = 0; s < 3; ++s) {
    const int R = Rs[s];
    const _Float16* Ap = G16 + ((size_t)s << 18);
    const _Float16* Bp = T16 + ((size_t)(s * NSL + slice) << 18);
    int klo = bm - R;
    klo = (klo > 0 ? klo : 0) >> 5;
    int khi = bm + 127 + R;
    if (khi > 511) khi = 511;
    khi >>= 5;

    f32x4 acc[4][4];
#pragma unroll
    for (int i = 0; i < 4; ++i)
#pragma unroll
      for (int j = 0; j < 4; ++j) acc[i][j] = (f32x4){0.f, 0.f, 0.f, 0.f};

    BARRIER();  // protect buffers 0/1 from previous sigma's late readers
    K_PIPELINE_LOOP();

#pragma unroll
    for (int fm = 0; fm < 4; ++fm)
#pragma unroll
      for (int fn = 0; fn < 4; ++fn)
#pragma unroll
        for (int j = 0; j < 4; ++j)
          res[fm][fn][j] += w3 * __logf(acc[fm][fn][j] + 1.f);
  }

  // write out + fused per-channel min/max
  float mn = 3.4e38f, mx = -3.4e38f;
#pragma unroll
  for (int fm = 0; fm < 4; ++fm)
#pragma unroll
    for (int fn = 0; fn < 4; ++fn) {
      const int rb = bm + (wr << 6) + (fm << 4) + (lg << 2);
      const int cg = bn + (wc << 6) + (fn << 4) + lr;
      float* op = out + ((size_t)slice << 18) + ((size_t)rb << 9) + cg;
#pragma unroll
      for (int j = 0; j < 4; ++j) {
        const float v = res[fm][fn][j];
        op[j << 9] = v;
        mn = fminf(mn, v);
        mx = fmaxf(mx, v);
      }
    }
#pragma unroll
  for (int off = 32; off > 0; off >>= 1) {
    mn = fminf(mn, __shfl_xor(mn, off));
    mx = fmaxf(mx, __shfl_xor(mx, off));
  }
  if (lane == 0) {
    smn[wave] = mn;
    smx[wave] = mx;
  }
  __syncthreads();
  if (t == 0) {
    mn = fminf(fminf(smn[0], smn[1]), fminf(smn[2], smn[3]));
    mx = fmaxf(fmaxf(smx[0], smx[1]), fmaxf(smx[2], smx[3]));
    const int ch = slice % 3;
    atomicMin(&mm[ch], __float_as_uint(mn));  // values >= 0
    atomicMax(&mm[3 + ch], __float_as_uint(mx));
  }
}

// ---------------- normalize ----------------
__global__ __launch_bounds__(256) void norm_k(float* __restrict__ r,
                                              const unsigned* __restrict__ mm) {
  const int b = blockIdx.x;
  const int slice = b >> 4;
  const int piece = b & 15;
  const int ch = slice % 3;
  const float mn = __uint_as_float(mm[ch]);
  const float mx = __uint_as_float(mm[3 + ch]);
  const float inv = 1.f / (mx - mn);
  float* p = r + ((size_t)slice << 18) + (piece << 14);
  const int t = threadIdx.x;
  for (int q = 0; q < 16; ++q) {
    float4 v = *reinterpret_cast<const float4*>(&p[(q * 256 + t) << 2]);
    v.x = (v.x - mn) * inv;
    v.y = (v.y - mn) * inv;
    v.z = (v.z - mn) * inv;
    v.w = (v.w - mn) * inv;
    *reinterpret_cast<float4*>(&p[(q * 256 + t) << 2]) = v;
  }
}

extern "C" void kernel_launch(void* const* d_in, const int* in_sizes, int n_in,
                              void* d_out, int out_size, void* d_ws, size_t ws_size,
                              hipStream_t stream) {
  const float* img = (const float*)d_in[0];
  float* out = (float*)d_out;
  float* wsf = (float*)d_ws;
  unsigned* mm = (unsigned*)(wsf + MM_OFF);
  _Float16* G16 = (_Float16*)((char*)d_ws + G16_BYTE_OFF);
  _Float16* X16 = (_Float16*)((char*)d_ws + X16_BYTE_OFF);
  _Float16* T16 = (_Float16*)((char*)d_ws + T16_BYTE_OFF);

  wkern<<<3, 256, 0, stream>>>(wsf);
  mm_init<<<1, 64, 0, stream>>>(mm);
  gkern<<<dim3(512, 3), 256, 0, stream>>>(wsf, G16);
  xconv<<<6144, 256, 0, stream>>>(img, X16);

  gemm1_k<<<dim3(4, 4, 3 * NSL), 256, 0, stream>>>(X16, G16, T16);
  gemm2_k<<<dim3(4, 4, NSL), 256, 0, stream>>>(G16, T16, out, mm);

  norm_k<<<768, 256, 0, stream>>>(out, mm);
}